// Round 7
// baseline (291.214 us; speedup 1.0000x reference)
//
#include <hip/hip_runtime.h>
#include <hip/hip_bf16.h>

#define EPS 1e-7f

// Sizes (fixed per reference): B=64, Lc=512, La=64, Dc=Da=1024
#define B   64
#define LC  512
#define LA  64
#define D   1024
#define D4  256              // float4s per row
#define ROWS 16              // rows per half-chunk
#define HALVES 2             // halves per block in ctx_pass
#define CCH  (LC / (ROWS * HALVES))   // 16 chunks per b

// ---------------------------------------------------------------------------
// K1: per-(b, s) partial row-sums of asp_text. grid (4, B), block 256.
// Thread t owns float4 column t; sums 16 rows -> Ppart[(b*4+s)*D4 + t].
__global__ void k_asp_psum(const float* __restrict__ A, float* __restrict__ P) {
    int b = blockIdx.y, s = blockIdx.x, t = threadIdx.x;
    const float4* Ab = reinterpret_cast<const float4*>(A + (size_t)b * LA * D);
    float sx = 0.f, sy = 0.f, sz = 0.f, sw = 0.f;
    #pragma unroll
    for (int r = 0; r < ROWS; ++r) {
        float4 v = Ab[(s * ROWS + r) * D4 + t];
        sx += v.x; sy += v.y; sz += v.z; sw += v.w;
    }
    float4 o; o.x = sx; o.y = sy; o.z = sz; o.w = sw;
    reinterpret_cast<float4*>(P)[(b * 4 + s) * D4 + t] = o;
}

// ---------------------------------------------------------------------------
// K2/K4: V[b][d] = sum_e W[d][e] * x[b][e].
// COMBINE=1: x[b][e] = (sum_s Ppart[b*4+s][e]) / LA  (combine fused, scale at end)
// grid (128, 4), block 256. Wave owns 2 W-rows in regs; streams 16 b's.
template <int COMBINE>
__global__ void k_matvec(const float* __restrict__ W, const float* __restrict__ X,
                         float* __restrict__ V) {
    int w    = threadIdx.x >> 6;
    int lane = threadIdx.x & 63;
    int d0   = (blockIdx.x * 4 + w) * 2;      // [0, 1024) even
    int b0   = blockIdx.y * 16;

    float4 w0[4], w1[4];
    const float4* Wr0 = reinterpret_cast<const float4*>(W + (size_t)d0 * D);
    const float4* Wr1 = reinterpret_cast<const float4*>(W + (size_t)(d0 + 1) * D);
    #pragma unroll
    for (int k = 0; k < 4; ++k) { w0[k] = Wr0[lane + 64 * k]; w1[k] = Wr1[lane + 64 * k]; }

    #pragma unroll 4
    for (int bb = 0; bb < 16; ++bb) {
        int b = b0 + bb;
        float p0 = 0.f, p1 = 0.f;
        #pragma unroll
        for (int k = 0; k < 4; ++k) {
            float4 x;
            if (COMBINE) {
                const float4* P4 = reinterpret_cast<const float4*>(X);
                float4 a0 = P4[(b * 4 + 0) * D4 + lane + 64 * k];
                float4 a1 = P4[(b * 4 + 1) * D4 + lane + 64 * k];
                float4 a2 = P4[(b * 4 + 2) * D4 + lane + 64 * k];
                float4 a3 = P4[(b * 4 + 3) * D4 + lane + 64 * k];
                x.x = a0.x + a1.x + a2.x + a3.x;
                x.y = a0.y + a1.y + a2.y + a3.y;
                x.z = a0.z + a1.z + a2.z + a3.z;
                x.w = a0.w + a1.w + a2.w + a3.w;
            } else {
                x = reinterpret_cast<const float4*>(X + (size_t)b * D)[lane + 64 * k];
            }
            p0 += x.x * w0[k].x + x.y * w0[k].y + x.z * w0[k].z + x.w * w0[k].w;
            p1 += x.x * w1[k].x + x.y * w1[k].y + x.z * w1[k].z + x.w * w1[k].w;
        }
        #pragma unroll
        for (int m = 1; m < 64; m <<= 1) {
            p0 += __shfl_xor(p0, m, 64);
            p1 += __shfl_xor(p1, m, 64);
        }
        if (lane == 0) {
            const float s = COMBINE ? (1.0f / (float)LA) : 1.0f;
            V[b * D + d0] = p0 * s; V[b * D + d0 + 1] = p1 * s;
        }
    }
}

// ---------------------------------------------------------------------------
// K3: fused context pass. grid (16, B) = 1024 blocks, block 256 (4 waves),
// 16 waves/CU. Block handles 32 rows as 2 halves of 16; x rows in registers.
__global__ __launch_bounds__(256, 4)
void k_ctx_pass(const float* __restrict__ C, const float* __restrict__ vc,
                const float* __restrict__ cb,
                float* __restrict__ pacc, float* __restrict__ psum,
                float* __restrict__ pesum) {
    __shared__ float sdot[HALVES][ROWS][4];
    __shared__ float se[HALVES][ROWS];
    int b = blockIdx.y, c = blockIdx.x;
    int w    = threadIdx.x >> 6;
    int lane = threadIdx.x & 63;
    int f4   = w * 64 + lane;                 // float4 index within row [0,256)

    float4 vr = reinterpret_cast<const float4*>(vc + (size_t)b * D)[f4];

    float4 acc = {0.f, 0.f, 0.f, 0.f}, sct = {0.f, 0.f, 0.f, 0.f};
    float es_local = 0.f;                      // valid on threads 0..15

    const float4* Cb0 = reinterpret_cast<const float4*>(
        C + ((size_t)b * LC + (size_t)c * ROWS * HALVES) * D);

    #pragma unroll
    for (int h = 0; h < HALVES; ++h) {
        const float4* Cb = Cb0 + (size_t)h * ROWS * D4;
        float4 x[ROWS];
        #pragma unroll
        for (int r = 0; r < ROWS; ++r) x[r] = Cb[r * D4 + f4];   // 16 indep loads

        #pragma unroll
        for (int r = 0; r < ROWS; ++r) {
            float p = x[r].x * vr.x + x[r].y * vr.y + x[r].z * vr.z + x[r].w * vr.w;
            #pragma unroll
            for (int m = 1; m < 64; m <<= 1) p += __shfl_xor(p, m, 64);
            if (lane == 0) sdot[h][r][w] = p;
        }
        __syncthreads();
        if (threadIdx.x < ROWS) {
            int r = threadIdx.x;
            float s = sdot[h][r][0] + sdot[h][r][1] + sdot[h][r][2] + sdot[h][r][3];
            float e = expf(tanhf(s + cb[(c * HALVES + h) * ROWS + r]));
            se[h][r] = e;
            es_local += e;
        }
        __syncthreads();
        #pragma unroll
        for (int r = 0; r < ROWS; ++r) {
            float e = se[h][r];
            acc.x += e * x[r].x; acc.y += e * x[r].y;
            acc.z += e * x[r].z; acc.w += e * x[r].w;
            sct.x += x[r].x;     sct.y += x[r].y;
            sct.z += x[r].z;     sct.w += x[r].w;
        }
    }

    int pidx = b * CCH + c;
    reinterpret_cast<float4*>(pacc)[pidx * D4 + f4] = acc;
    reinterpret_cast<float4*>(psum)[pidx * D4 + f4] = sct;
    if (w == 0) {
        float e2 = (lane < ROWS) ? es_local : 0.f;
        #pragma unroll
        for (int m = 1; m < 64; m <<= 1) e2 += __shfl_xor(e2, m, 64);
        if (lane == 0) pesum[pidx] = e2;
    }
}

// ---------------------------------------------------------------------------
// K3b: reduce partials -> attend_context (out cols [0,1024)) + context_avg.
// grid (4, B), block 64. Block (q,b) owns float4 range [q*64, q*64+64).
__global__ void k_ctx_reduce(const float* __restrict__ pacc, const float* __restrict__ psum,
                             const float* __restrict__ pesum,
                             float* __restrict__ out, float* __restrict__ ctx_avg) {
    int b = blockIdx.y, q = blockIdx.x;
    int f4 = q * 64 + threadIdx.x;
    float ax = 0.f, ay = 0.f, az = 0.f, aw = 0.f;
    float sx = 0.f, sy = 0.f, sz = 0.f, sw = 0.f;
    const float4* pa = reinterpret_cast<const float4*>(pacc);
    const float4* ps = reinterpret_cast<const float4*>(psum);
    #pragma unroll
    for (int c = 0; c < CCH; ++c) {
        float4 va = pa[(b * CCH + c) * D4 + f4];
        float4 vs = ps[(b * CCH + c) * D4 + f4];
        ax += va.x; ay += va.y; az += va.z; aw += va.w;
        sx += vs.x; sy += vs.y; sz += vs.z; sw += vs.w;
    }
    float es = 0.f;
    #pragma unroll
    for (int c = 0; c < CCH; ++c) es += pesum[b * CCH + c];
    float inv = 1.0f / (es + EPS);
    float4 o; o.x = ax * inv; o.y = ay * inv; o.z = az * inv; o.w = aw * inv;
    reinterpret_cast<float4*>(out)[b * (2 * D4) + f4] = o;          // attend_context
    const float invL = 1.0f / (float)LC;
    float4 m; m.x = sx * invL; m.y = sy * invL; m.z = sz * invL; m.w = sw * invL;
    reinterpret_cast<float4*>(ctx_avg)[b * D4 + f4] = m;
}

// ---------------------------------------------------------------------------
// K5a: aspect scores. grid (4, B), block 256. Block (q,b): rows [q*16, q*16+16).
// pesumA[b*4+q] = sum_r exp(tanh(<row, v_t> + ab)).
__global__ void k_asp_score(const float* __restrict__ A, const float* __restrict__ vt,
                            const float* __restrict__ ab, float* __restrict__ pesumA) {
    __shared__ float sdot[ROWS][4];
    __shared__ float se[ROWS];
    int b = blockIdx.y, q = blockIdx.x;
    int w    = threadIdx.x >> 6;
    int lane = threadIdx.x & 63;
    int f4   = w * 64 + lane;

    float4 vr = reinterpret_cast<const float4*>(vt + (size_t)b * D)[f4];
    const float4* Ab = reinterpret_cast<const float4*>(A + ((size_t)b * LA + q * ROWS) * D);
    #pragma unroll
    for (int r = 0; r < ROWS; ++r) {
        float4 x = Ab[r * D4 + f4];
        float p = x.x * vr.x + x.y * vr.y + x.z * vr.z + x.w * vr.w;
        #pragma unroll
        for (int m = 1; m < 64; m <<= 1) p += __shfl_xor(p, m, 64);
        if (lane == 0) sdot[r][w] = p;
    }
    __syncthreads();
    if (threadIdx.x < ROWS) {
        int r = threadIdx.x;
        float s = sdot[r][0] + sdot[r][1] + sdot[r][2] + sdot[r][3];
        se[r] = expf(tanhf(s + ab[q * ROWS + r]));
    }
    __syncthreads();
    if (w == 0) {
        float e2 = (lane < ROWS) ? se[lane] : 0.f;
        #pragma unroll
        for (int m = 1; m < 64; m <<= 1) e2 += __shfl_xor(e2, m, 64);
        if (lane == 0) pesumA[b * 4 + q] = e2;
    }
}

// K5b: attend_asp[b,d] = (sum_q pesumA + EPS) * rowsum(asp_text)[b,d]
//      (a_t_sum * La * asp_avg == a_t_sum * rowsum; 1/La cancels)
// grid (B), block 256. rowsum read from the 4 Ppart partials.
__global__ void k_asp_scale(const float* __restrict__ pesumA, const float* __restrict__ P,
                            float* __restrict__ out) {
    int b = blockIdx.x, t = threadIdx.x;
    float es = pesumA[b * 4 + 0] + pesumA[b * 4 + 1] + pesumA[b * 4 + 2] + pesumA[b * 4 + 3];
    float scale = es + EPS;
    const float4* P4 = reinterpret_cast<const float4*>(P);
    float4 a0 = P4[(b * 4 + 0) * D4 + t];
    float4 a1 = P4[(b * 4 + 1) * D4 + t];
    float4 a2 = P4[(b * 4 + 2) * D4 + t];
    float4 a3 = P4[(b * 4 + 3) * D4 + t];
    float4 o;
    o.x = (a0.x + a1.x + a2.x + a3.x) * scale;
    o.y = (a0.y + a1.y + a2.y + a3.y) * scale;
    o.z = (a0.z + a1.z + a2.z + a3.z) * scale;
    o.w = (a0.w + a1.w + a2.w + a3.w) * scale;
    reinterpret_cast<float4*>(out)[b * (2 * D4) + D4 + t] = o;
}

// ---------------------------------------------------------------------------
extern "C" void kernel_launch(void* const* d_in, const int* in_sizes, int n_in,
                              void* d_out, int out_size, void* d_ws, size_t ws_size,
                              hipStream_t stream) {
    const float* context   = (const float*)d_in[0];
    const float* asp_text  = (const float*)d_in[1];
    const float* context_w = (const float*)d_in[2];
    const float* context_b = (const float*)d_in[3];
    const float* aspect_w  = (const float*)d_in[4];
    const float* aspect_b  = (const float*)d_in[5];
    float* out = (float*)d_out;
    float* ws  = (float*)d_ws;

    // workspace layout (floats)
    float* v_c     = ws;                        // 64*1024
    float* ctx_avg = v_c + B * D;               // 64*1024
    float* v_t     = ctx_avg + B * D;           // 64*1024
    float* Ppart   = v_t + B * D;               // 4*64*1024
    float* pacc    = Ppart + 4 * B * D;         // 1024*1024
    float* psum    = pacc + (size_t)B * CCH * D;  // 1024*1024
    float* pesum   = psum + (size_t)B * CCH * D;  // 1024
    float* pesumA  = pesum + B * CCH;           // 256

    k_asp_psum   <<<dim3(4, B),   256, 0, stream>>>(asp_text, Ppart);
    k_matvec<1>  <<<dim3(128, 4), 256, 0, stream>>>(context_w, Ppart, v_c);
    k_ctx_pass   <<<dim3(CCH, B), 256, 0, stream>>>(context, v_c, context_b,
                                                    pacc, psum, pesum);
    k_ctx_reduce <<<dim3(4, B),   64,  0, stream>>>(pacc, psum, pesum, out, ctx_avg);
    k_matvec<0>  <<<dim3(128, 4), 256, 0, stream>>>(aspect_w, ctx_avg, v_t);
    k_asp_score  <<<dim3(4, B),   256, 0, stream>>>(asp_text, v_t, aspect_b, pesumA);
    k_asp_scale  <<<B,            256, 0, stream>>>(pesumA, Ppart, out);
}